// Round 1
// baseline (17076.021 us; speedup 1.0000x reference)
//
#include <hip/hip_runtime.h>
#include <hip/hip_bf16.h>

// Problem dims
#define S_  128
#define B_  32
#define V_  33278
#define E_  400
#define H_  1150
#define SB_ (S_*B_)        // 4096 rows
#define EP_ 416            // E padded to x32
#define HP_ 1152           // H padded to x32
#define G0_ (4*H_)         // 4600 gates, layers 0/1
#define G2_ (4*E_)         // 1600 gates, layer 2

typedef __attribute__((ext_vector_type(8))) short short8;   // 8 bf16 (4 VGPRs)
typedef __attribute__((ext_vector_type(4))) float f32x4;

// dst[r][0..Kpad) = (k<K ? w*m : 0)   (fp32 masked recurrent weights, zero pad)
__global__ __launch_bounds__(256) void k_maskmul(const float* __restrict__ w,
    const float* __restrict__ m, float* __restrict__ dst, int K, int Kpad) {
  int r = blockIdx.y;
  int k = blockIdx.x * 256 + threadIdx.x;
  if (k >= Kpad) return;
  dst[(size_t)r * Kpad + k] = (k < K) ? w[(size_t)r * K + k] * m[(size_t)r * K + k] : 0.f;
}

// dst[r][0..Kpad) = bf16(k<K ? src : 0)
__global__ __launch_bounds__(256) void k_castpad(const float* __restrict__ src,
    __hip_bfloat16* __restrict__ dst, int K, int Kpad) {
  int r = blockIdx.y;
  int k = blockIdx.x * 256 + threadIdx.x;
  if (k >= Kpad) return;
  float v = (k < K) ? src[(size_t)r * K + k] : 0.f;
  dst[(size_t)r * Kpad + k] = __float2bfloat16(v);
}

// X[r][0..EP) = bf16(emb[tokens[r]][e]) (zero pad cols)
__global__ __launch_bounds__(64) void k_embed(const int* __restrict__ tok,
    const float* __restrict__ emb, __hip_bfloat16* __restrict__ X) {
  int r = blockIdx.x;
  int t = tok[r];
  const float* er = emb + (size_t)t * E_;
  __hip_bfloat16* xr = X + (size_t)r * EP_;
  for (int e = threadIdx.x; e < EP_; e += 64)
    xr[e] = __float2bfloat16(e < E_ ? er[e] : 0.f);
}

// C[M][N] = A[M][Kpad](bf16) * B[N][Kpad](bf16)^T + bias[N]   (fp32 out)
// 128x128 tile, 4 waves in 2x2, each wave 64x64 via 4x4 mfma_f32_16x16x32_bf16.
__global__ __launch_bounds__(256) void k_gemm_nt(
    const __hip_bfloat16* __restrict__ A, const __hip_bfloat16* __restrict__ Bm,
    const float* __restrict__ bias, float* __restrict__ C,
    int M, int N, int Kpad) {
  __shared__ short As[128][40];   // +8 pad
  __shared__ short Bs[128][40];
  const int tid = threadIdx.x;
  const int m0 = blockIdx.y * 128;
  const int n0 = blockIdx.x * 128;
  const int wv = tid >> 6, ln = tid & 63;
  const int wm = (wv >> 1) * 64, wn = (wv & 1) * 64;
  const int fr = ln & 15, fq = ln >> 4;   // frag row / quad
  const short* Ag = (const short*)A;
  const short* Bg = (const short*)Bm;
  f32x4 acc[4][4] = {};
  for (int k0 = 0; k0 < Kpad; k0 += 32) {
    // stage 128x32 bf16 tiles: 512 chunks of 8 bf16, 2 per thread
#pragma unroll
    for (int i = 0; i < 2; ++i) {
      int chunk = tid + 256 * i;
      int r = chunk >> 2, q = (chunk & 3) * 8;
      *(short8*)&As[r][q] = *(const short8*)(Ag + (size_t)(m0 + r) * Kpad + k0 + q);
      short8 bv = {};
      if (n0 + r < N) bv = *(const short8*)(Bg + (size_t)(n0 + r) * Kpad + k0 + q);
      *(short8*)&Bs[r][q] = bv;
    }
    __syncthreads();
    short8 af[4], bfr[4];
#pragma unroll
    for (int i = 0; i < 4; ++i) {
      af[i]  = *(const short8*)&As[wm + i * 16 + fr][fq * 8];
      bfr[i] = *(const short8*)&Bs[wn + i * 16 + fr][fq * 8];
    }
#pragma unroll
    for (int i = 0; i < 4; ++i)
#pragma unroll
      for (int j = 0; j < 4; ++j)
        acc[i][j] = __builtin_amdgcn_mfma_f32_16x16x32_bf16(af[i], bfr[j], acc[i][j], 0, 0, 0);
    __syncthreads();
  }
  // D: col = lane&15, row = (lane>>4)*4 + reg
#pragma unroll
  for (int i = 0; i < 4; ++i)
#pragma unroll
    for (int j = 0; j < 4; ++j)
#pragma unroll
      for (int r = 0; r < 4; ++r) {
        int m = m0 + wm + i * 16 + fq * 4 + r;
        int n = n0 + wn + j * 16 + fr;
        if (n < N) C[(size_t)m * N + n] = acc[i][j][r] + bias[n];
      }
}

// One LSTM time step. grid = Hh blocks (one per hidden unit), block = 64:
// lanes 0..31 = batch b (K-half 0), lanes 32..63 = same b, K-half 1.
// hprev layout [Kpad][32] (transposed) -> coalesced row reads; hnew written
// to the other buffer (double-buffered across steps to avoid RAW race).
__global__ __launch_bounds__(64) void k_step(
    const float* __restrict__ xp,   // [SB][4*Hh]
    const float* __restrict__ wm,   // [4*Hh][Kpad] masked fp32, pad cols zero
    const float* __restrict__ bhh,  // [4*Hh]
    const float* __restrict__ hprev,// [Kpad][32]
    float* __restrict__ hnew,       // [Kpad][32]
    float* __restrict__ cT,         // [Hh][32]
    __hip_bfloat16* __restrict__ Xout, // [SB][Wout]
    int Hh, int Kpad, int Wout, int s, int first) {
  const int b  = threadIdx.x & 31;
  const int kh = threadIdx.x >> 5;
  const int u  = blockIdx.x;
  float a0 = 0.f, a1 = 0.f, a2 = 0.f, a3 = 0.f;
  if (!first) {
    const int Kh = Kpad >> 1;
    const int kbeg = kh * Kh;
    const float* w0 = wm + (size_t)u * Kpad + kbeg;
    const float* w1 = wm + ((size_t)Hh + u) * Kpad + kbeg;
    const float* w2 = wm + ((size_t)2 * Hh + u) * Kpad + kbeg;
    const float* w3 = wm + ((size_t)3 * Hh + u) * Kpad + kbeg;
    const float* hp = hprev + (size_t)kbeg * 32 + b;
    for (int k = 0; k < Kh; k += 4) {
      float h0 = hp[(k + 0) * 32];
      float h1 = hp[(k + 1) * 32];
      float h2 = hp[(k + 2) * 32];
      float h3 = hp[(k + 3) * 32];
      float4 w;
      w = *(const float4*)(w0 + k); a0 += w.x * h0 + w.y * h1 + w.z * h2 + w.w * h3;
      w = *(const float4*)(w1 + k); a1 += w.x * h0 + w.y * h1 + w.z * h2 + w.w * h3;
      w = *(const float4*)(w2 + k); a2 += w.x * h0 + w.y * h1 + w.z * h2 + w.w * h3;
      w = *(const float4*)(w3 + k); a3 += w.x * h0 + w.y * h1 + w.z * h2 + w.w * h3;
    }
    a0 += __shfl_down(a0, 32);
    a1 += __shfl_down(a1, 32);
    a2 += __shfl_down(a2, 32);
    a3 += __shfl_down(a3, 32);
  }
  if (kh == 0) {
    size_t row = (size_t)s * 32 + b;
    const float* xr = xp + row * (size_t)(4 * Hh);
    float gi = xr[u]          + bhh[u]          + a0;
    float gf = xr[Hh + u]     + bhh[Hh + u]     + a1;
    float gg = xr[2 * Hh + u] + bhh[2 * Hh + u] + a2;
    float go = xr[3 * Hh + u] + bhh[3 * Hh + u] + a3;
    float si = 1.f / (1.f + expf(-gi));
    float sf = 1.f / (1.f + expf(-gf));
    float so = 1.f / (1.f + expf(-go));
    float tg = tanhf(gg);
    float c = first ? (si * tg) : fmaf(sf, cT[u * 32 + b], si * tg);
    float h = so * tanhf(c);
    cT[u * 32 + b] = c;
    hnew[u * 32 + b] = h;
    Xout[row * Wout + u] = __float2bfloat16(h);
  }
}

extern "C" void kernel_launch(void* const* d_in, const int* in_sizes, int n_in,
                              void* d_out, int out_size, void* d_ws, size_t ws_size,
                              hipStream_t stream) {
  const int*   tokens = (const int*)  d_in[0];
  const float* emb    = (const float*)d_in[1];
  const float* fc_b   = (const float*)d_in[2];
  const float* w_ih0  = (const float*)d_in[3];
  const float* w_hh0  = (const float*)d_in[4];
  const float* b_ih0  = (const float*)d_in[5];
  const float* b_hh0  = (const float*)d_in[6];
  const float* w_ih1  = (const float*)d_in[7];
  const float* w_hh1  = (const float*)d_in[8];
  const float* b_ih1  = (const float*)d_in[9];
  const float* b_hh1  = (const float*)d_in[10];
  const float* w_ih2  = (const float*)d_in[11];
  const float* w_hh2  = (const float*)d_in[12];
  const float* b_ih2  = (const float*)d_in[13];
  const float* b_hh2  = (const float*)d_in[14];
  const float* mask0  = (const float*)d_in[15];
  const float* mask1  = (const float*)d_in[16];
  const float* mask2  = (const float*)d_in[17];
  float* out = (float*)d_out;

  char* ws = (char*)d_ws;
  size_t off = 0;
  auto alloc = [&](size_t bytes) {
    void* p = ws + off;
    off += (bytes + 255) & ~(size_t)255;
    return p;
  };
  __hip_bfloat16* XA   = (__hip_bfloat16*)alloc((size_t)SB_ * HP_ * 2);
  __hip_bfloat16* XB   = (__hip_bfloat16*)alloc((size_t)SB_ * HP_ * 2);
  float* XP   = (float*)alloc((size_t)SB_ * G0_ * 4);
  float* hT0  = (float*)alloc((size_t)HP_ * B_ * 4);
  float* hT1  = (float*)alloc((size_t)HP_ * B_ * 4);
  float* cT   = (float*)alloc((size_t)HP_ * B_ * 4);
  float* wm0  = (float*)alloc((size_t)G0_ * HP_ * 4);
  float* wm1  = (float*)alloc((size_t)G0_ * HP_ * 4);
  float* wm2  = (float*)alloc((size_t)G2_ * E_ * 4);
  __hip_bfloat16* wih0b = (__hip_bfloat16*)alloc((size_t)G0_ * EP_ * 2);
  __hip_bfloat16* wih1b = (__hip_bfloat16*)alloc((size_t)G0_ * HP_ * 2);
  __hip_bfloat16* wih2b = (__hip_bfloat16*)alloc((size_t)G2_ * HP_ * 2);
  __hip_bfloat16* embb  = (__hip_bfloat16*)alloc((size_t)V_ * EP_ * 2);
  if (off > ws_size) return;  // workspace too small: bail (test will fail loudly)

  // Weight prep (every call: masks reapplied, pads zeroed)
  k_maskmul<<<dim3((HP_ + 255) / 256, G0_), 256, 0, stream>>>(w_hh0, mask0, wm0, H_, HP_);
  k_maskmul<<<dim3((HP_ + 255) / 256, G0_), 256, 0, stream>>>(w_hh1, mask1, wm1, H_, HP_);
  k_maskmul<<<dim3((E_ + 255) / 256,  G2_), 256, 0, stream>>>(w_hh2, mask2, wm2, E_, E_);
  k_castpad<<<dim3((EP_ + 255) / 256, G0_), 256, 0, stream>>>(w_ih0, wih0b, E_, EP_);
  k_castpad<<<dim3((HP_ + 255) / 256, G0_), 256, 0, stream>>>(w_ih1, wih1b, H_, HP_);
  k_castpad<<<dim3((HP_ + 255) / 256, G2_), 256, 0, stream>>>(w_ih2, wih2b, H_, HP_);
  k_castpad<<<dim3((EP_ + 255) / 256, V_),  256, 0, stream>>>(emb,   embb,  E_, EP_);

  // Embedding -> XA [SB][EP] bf16
  k_embed<<<SB_, 64, 0, stream>>>(tokens, emb, XA);

  // Layer 0: xp = XA @ w_ih0^T + b_ih0 ; recurrence -> XB
  k_gemm_nt<<<dim3(36, 32), 256, 0, stream>>>(XA, wih0b, b_ih0, XP, SB_, G0_, EP_);
  for (int s = 0; s < S_; ++s) {
    float* hp = (s & 1) ? hT1 : hT0;
    float* hn = (s & 1) ? hT0 : hT1;
    k_step<<<H_, 64, 0, stream>>>(XP, wm0, b_hh0, hp, hn, cT, XB, H_, HP_, HP_, s, s == 0);
  }
  // Layer 1 -> XA
  k_gemm_nt<<<dim3(36, 32), 256, 0, stream>>>(XB, wih1b, b_ih1, XP, SB_, G0_, HP_);
  for (int s = 0; s < S_; ++s) {
    float* hp = (s & 1) ? hT1 : hT0;
    float* hn = (s & 1) ? hT0 : hT1;
    k_step<<<H_, 64, 0, stream>>>(XP, wm1, b_hh1, hp, hn, cT, XA, H_, HP_, HP_, s, s == 0);
  }
  // Layer 2 (hidden = E) -> XB
  k_gemm_nt<<<dim3(13, 32), 256, 0, stream>>>(XA, wih2b, b_ih2, XP, SB_, G2_, HP_);
  for (int s = 0; s < S_; ++s) {
    float* hp = (s & 1) ? hT1 : hT0;
    float* hn = (s & 1) ? hT0 : hT1;
    k_step<<<E_, 64, 0, stream>>>(XP, wm2, b_hh2, hp, hn, cT, XB, E_, E_, EP_, s, s == 0);
  }
  // Output projection: out = XB @ emb^T + fc_bias  [4096][33278] fp32
  k_gemm_nt<<<dim3(260, 32), 256, 0, stream>>>(XB, embb, fc_b, out, SB_, V_, EP_);
}